// Round 9
// baseline (265.051 us; speedup 1.0000x reference)
//
#include <hip/hip_runtime.h>
#include <math.h>

// B=4, H=256, W=256, 100 iters. Closed-form update (3-pt GH quadrature is
// exact for these degree<=4 integrands; log/NDC terms cancel):
//   dmu  = 2*uw1*mu + uw2*y + sum_edges ew*mu_nb
//   dsg  = 2*uw1*sg + sum_edges ew*rou_edge*sg_nb
//   drou = ew*sg_self*sg_nb        (per owned edge)
// Temporal blocking: T=10 iters/launch, 52x52 halo tile -> 32x32 interior,
// 256 blocks (1/CU).
// Round 9: wave-per-rowgroup mapping (rg = tid>>6, col = lane&63; cols >=52
// dead). Left/right neighbors come from DPP wavefront shifts (VALU pipe,
// ~3% busy) instead of ds_read_b128 (the bound pipe): update_dpp 0x138
// (wf_shr1: lane i <- i-1) for left, 0x130 (wf_shl1: lane i <- i+1) for
// right. LDS now carries ONLY rowgroup-boundary rows as float2 {mu,sg} /
// {mu, rou0*sg}: 4 b64 ops/thread-iter vs 14 b128 — ~1776 -> ~416 LDS
// cyc/iter. Boundary-lane garbage (DPP bound, tile edges, dead cols) is
// harmless by shrinking-validity; everything is clamp-bounded (no NaN).
#define NPIX  262144
#define NEDGE 524288
#define ITERS 100
#define T     10
#define TILE  52            // 32 + 2*T
#define NRG   13            // rowgroups of 4 rows: 13*4 = 52 exact
#define INT_LO T            // interior rows/cols [10, 42)
#define INT_HI (T+32)

__device__ __forceinline__ float clampf(float x, float lo, float hi) {
    return fminf(fmaxf(x, lo), hi);
}
// lane i <- lane i-1 (lane 0 keeps own value): left neighbor
__device__ __forceinline__ float dpp_shr1(float x) {
    int i = __builtin_bit_cast(int, x);
    int r = __builtin_amdgcn_update_dpp(i, i, 0x138, 0xf, 0xf, false);
    return __builtin_bit_cast(float, r);
}
// lane i <- lane i+1 (lane 63 keeps own value): right neighbor
__device__ __forceinline__ float dpp_shl1(float x) {
    int i = __builtin_bit_cast(int, x);
    int r = __builtin_amdgcn_update_dpp(i, i, 0x130, 0xf, 0xf, false);
    return __builtin_bit_cast(float, r);
}

// State float4 {mu, sigma, rou0(down-edge), rou1(right-edge)}.
// c1 = {2*uw1, uw2*y, ew0, ew1}.
__global__ __launch_bounds__(1024, 4) void tile_kernel(
    const float4* __restrict__ stI, const float4* __restrict__ vI,
    float4* __restrict__ stO, float4* __restrict__ vO,
    const float4* __restrict__ c1,
    float* __restrict__ mu_out,   // non-null on last launch (st/v not stored)
    int first)                    // launch 0: v := 0, vI not read
{
    // boundary-row exchange buffers (double-buffered) + one-time ew exchange
    __shared__ float2 bnd0[2][NRG*64];   // strip row 0: {mu, sg}
    __shared__ float2 bnd3[2][NRG*64];   // strip row 3: {mu, rou0*sg}
    __shared__ float  exch[NRG*64];      // one-time: row-3 ew0 per strip

    int tid  = threadIdx.x;
    int rg   = tid >> 6;          // one wave == one rowgroup (wave-uniform act)
    int lane = tid & 63;          // col in tile (52..63 dead)
    bool act = (rg < NRG);
    int bz = blockIdx.z;
    int h0 = blockIdx.y * 32;
    int w0 = blockIdx.x * 32;
    int w  = (w0 + lane - T) & 255;
    int me = rg*64 + lane;

    float4 st[4], v[4], k1[4];
    float  k2y[4];                // left-nb ew1 per row (via DPP, one-time)
    float  k2x0;                  // up-nb ew0 for strip row 0 (via LDS, one-time)
    int    gidx[4];

    // ---- one-time load: st, v, c1 -> registers ----
    if (act) {
#pragma unroll
        for (int k = 0; k < 4; ++k) {
            int r = 4*rg + k;
            int h = (h0 + r - T) & 255;
            int g = (bz << 16) | (h << 8) | w;
            gidx[k] = g;
            st[k] = stI[g];
            k1[k] = c1[g];
            k2y[k] = dpp_shr1(k1[k].w);       // left px's ew1
            v[k] = first ? make_float4(0.f, 0.f, 0.f, 0.f) : vI[g];
        }
        exch[me] = k1[3].z;                    // my row-3 ew0 for rg+1
        bnd0[0][me] = make_float2(st[0].x, st[0].y);
        bnd3[0][me] = make_float2(st[3].x, st[3].z*st[3].y);
    }
    __syncthreads();
    if (act)
        k2x0 = exch[((rg == 0) ? 0 : rg-1)*64 + lane];  // (rg-1)'s row-3 ew0

    // ---- T fused Jacobi iterations, one barrier each ----
    for (int s = 0; s < T; ++s) {
        int cb = s & 1;
        if (act) {
            float2 up_e = bnd3[cb][((rg == 0)     ? 0     : rg-1)*64 + lane];
            float2 dn_e = bnd0[cb][((rg == NRG-1) ? NRG-1 : rg+1)*64 + lane];
            float t[4], t2[4];
#pragma unroll
            for (int k = 0; k < 4; ++k) {
                t[k]  = st[k].w * st[k].y;     // rou1*sg  (for right-nb's dsg)
                t2[k] = st[k].z * st[k].y;     // rou0*sg  (for down-nb's dsg)
            }
            float4 ns[4]; float4 nv[4];
#pragma unroll
            for (int k = 0; k < 4; ++k) {
                float lf_mu = dpp_shr1(st[k].x);
                float lf_t  = dpp_shr1(t[k]);
                float rt_mu = dpp_shl1(st[k].x);
                float rt_sg = dpp_shl1(st[k].y);
                float up_mu = (k == 0) ? up_e.x : st[k-1].x;
                float up_t2 = (k == 0) ? up_e.y : t2[k-1];
                float dn_mu = (k == 3) ? dn_e.x : st[k+1].x;
                float dn_sg = (k == 3) ? dn_e.y : st[k+1].y;
                float4 S  = st[k];
                float4 K  = k1[k];
                float K2x = (k == 0) ? k2x0 : k1[k-1].z;  // up-nb ew0
                float K2y = k2y[k];                        // left-nb ew1
                float dmu = K.x*S.x + K.y + K.z*dn_mu + K.w*rt_mu
                          + K2x*up_mu + K2y*lf_mu;
                float dsg = K.x*S.y + K.z*S.z*dn_sg + K.w*S.w*rt_sg
                          + K2x*up_t2 + K2y*lf_t;
                float dr0 = K.z*S.y*dn_sg;
                float dr1 = K.w*S.y*rt_sg;
                float4 V = v[k];
                V.x = 0.7f*V.x + 0.01f*dmu;
                V.y = 0.7f*V.y + 0.01f*dsg;
                V.z = 0.7f*V.z + 0.01f*dr0;
                V.w = 0.7f*V.w + 0.01f*dr1;
                nv[k] = V;
                float4 o;
                o.x = clampf(S.x + V.x, 0.f, 63.f);
                o.y = clampf(S.y + V.y, 0.001f, 50.f);
                o.z = clampf(S.z + V.z, -0.99f, 0.99f);
                o.w = clampf(S.w + V.w, -0.99f, 0.99f);
                ns[k] = o;
            }
#pragma unroll
            for (int k = 0; k < 4; ++k) { st[k] = ns[k]; v[k] = nv[k]; }
            bnd0[cb ^ 1][me] = make_float2(st[0].x, st[0].y);
            bnd3[cb ^ 1][me] = make_float2(st[3].x, st[3].z*st[3].y);
        }
        __syncthreads();   // cb reads done everywhere; cb^1 writes visible
    }

    // ---- store interior (rows/cols [T, T+32)) ----
    if (act && lane >= INT_LO && lane < INT_HI) {
#pragma unroll
        for (int k = 0; k < 4; ++k) {
            int r = 4*rg + k;
            if (r >= INT_LO && r < INT_HI) {
                int g = gidx[k];
                if (mu_out) {
                    mu_out[g] = st[k].x;     // final launch: only mu needed
                } else {
                    stO[g] = st[k];
                    vO[g]  = v[k];
                }
            }
        }
    }
}

// ---- global max(edge_weight); gmax pre-zeroed via hipMemsetAsync ----
// (0u is the order-preserving encoding of the most-negative float)
__global__ void reduce_max_kernel(const float* __restrict__ ew, unsigned int* gmax) {
    int i = blockIdx.x*blockDim.x + threadIdx.x;
    float m = -INFINITY;
    for (; i < NEDGE; i += gridDim.x*blockDim.x) m = fmaxf(m, ew[i]);
#pragma unroll
    for (int off = 32; off > 0; off >>= 1)
        m = fmaxf(m, __shfl_down(m, off, 64));
    if ((threadIdx.x & 63) == 0) {
        unsigned u = __float_as_uint(m);
        unsigned key = (u & 0x80000000u) ? ~u : (u | 0x80000000u);
        atomicMax(gmax, key);
    }
}

// init state + invariant coefficient plane
__global__ __launch_bounds__(256) void init_state_kernel(
    const float*  __restrict__ y,
    const float2* __restrict__ ew,
    const float2* __restrict__ uw,
    const unsigned int* __restrict__ gmax_enc,
    float4* stA, float4* c1)
{
    int idx = blockIdx.x*256 + threadIdx.x;

    unsigned key = *gmax_enc;
    unsigned u = (key & 0x80000000u) ? (key ^ 0x80000000u) : ~key;
    float gmax = __uint_as_float(u);
    float inv_denom = 1.f / (gmax*1.01f + 1.f);   // one-time, IEEE div fine

    float2 e   = ew[idx];
    float2 uwv = uw[idx];
    float  yv  = y[idx];
    float4 st;
    st.x = yv;
    st.y = 1.f;
    st.z = e.x * inv_denom;
    st.w = e.y * inv_denom;
    stA[idx] = st;
    c1[idx]  = make_float4(2.f*uwv.x, uwv.y*yv, e.x, e.y);
}

extern "C" void kernel_launch(void* const* d_in, const int* in_sizes, int n_in,
                              void* d_out, int out_size, void* d_ws, size_t ws_size,
                              hipStream_t stream) {
    const float* y  = (const float*)d_in[0];
    const float* ew = (const float*)d_in[1];
    const float* uw = (const float*)d_in[2];
    float* out = (float*)d_out;
    const int N = NPIX;

    // workspace: stA, stB, vA, vB, c1 (float4 planes) + 1 uint (~21 MB)
    float4* stA = (float4*)d_ws;
    float4* stB = stA + N;
    float4* vA  = stB + N;
    float4* vB  = vA + N;
    float4* c1  = vB + N;
    unsigned int* gmax = (unsigned int*)(c1 + N);

    hipMemsetAsync(gmax, 0, sizeof(unsigned int), stream);
    hipLaunchKernelGGL(reduce_max_kernel, dim3(512), dim3(256), 0, stream, ew, gmax);
    hipLaunchKernelGGL(init_state_kernel, dim3(N/256), dim3(256), 0, stream,
                       y, (const float2*)ew, (const float2*)uw, gmax,
                       stA, c1);

    float4 *stI = stA, *stO = stB, *vI = vA, *vO = vB;
    const int NLAUNCH = ITERS / T;   // 10
    for (int l = 0; l < NLAUNCH; ++l) {
        float* mo = (l == NLAUNCH-1) ? out : nullptr;
        hipLaunchKernelGGL(tile_kernel, dim3(8, 8, 4), dim3(1024), 0, stream,
                           stI, vI, stO, vO, c1, mo, (l == 0) ? 1 : 0);
        float4* t;
        t = stI; stI = stO; stO = t;
        t = vI;  vI  = vO;  vO  = t;
    }
}